// Round 1
// baseline (870.274 us; speedup 1.0000x reference)
//
#include <hip/hip_runtime.h>

// ---------------------------------------------------------------------------
// LlamaAttention fused forward on MI355X (gfx950), bf16 MFMA pipeline:
//   1. hidden fp32 -> bf16
//   2. Wqkv, Wo fp32 -> bf16 transposed (B^T layout [N][K])
//   3. QKV = X @ Wqkv            (bf16 MFMA, 128x128 tile)
//   4. flash causal GQA attention (bf16 MFMA, online softmax)
//   5. out = AO @ Wo   (fp32 out)
// ---------------------------------------------------------------------------

#define S_LEN 2048
#define DMODEL 4096
#define EQKV 6144
#define NHEADS 32
#define NKV 8
#define HDIM 128

using bf16x8 = __attribute__((ext_vector_type(8))) short;
using f32x4  = __attribute__((ext_vector_type(4))) float;

__device__ __forceinline__ ushort f2bf(float f) {
  unsigned u = __float_as_uint(f);
  u += 0x7fffu + ((u >> 16) & 1u);   // round-to-nearest-even
  return (ushort)(u >> 16);
}

// ---------------- fp32 -> bf16 elementwise (vectorized) --------------------
__global__ __launch_bounds__(256) void cvt_f32_bf16(const float* __restrict__ in,
                                                    ushort* __restrict__ out, int n4) {
  int idx = blockIdx.x * 256 + threadIdx.x;
  if (idx < n4) {
    float4 v = ((const float4*)in)[idx];
    ushort4 o;
    o.x = f2bf(v.x); o.y = f2bf(v.y); o.z = f2bf(v.z); o.w = f2bf(v.w);
    ((ushort4*)out)[idx] = o;
  }
}

// ---------------- fp32 [K][N] -> bf16 [N][K] tiled transpose ---------------
__global__ __launch_bounds__(256) void transpose_cvt(const float* __restrict__ W,
                                                     ushort* __restrict__ WT,
                                                     int K, int N) {
  __shared__ float t[32][33];
  const int kb = blockIdx.x * 32, nb = blockIdx.y * 32;
  const int tx = threadIdx.x & 31, ty = threadIdx.x >> 5;  // ty 0..7
#pragma unroll
  for (int i = 0; i < 4; ++i)
    t[ty + i * 8][tx] = W[(size_t)(kb + ty + i * 8) * N + nb + tx];
  __syncthreads();
#pragma unroll
  for (int i = 0; i < 4; ++i)
    WT[(size_t)(nb + ty + i * 8) * K + kb + tx] = f2bf(t[tx][ty + i * 8]);
}

// ---------------- bf16 GEMM: C[M][N] = A[M][K] @ BT[N][K]^T ----------------
// 128x128 tile, BK=32, 4 waves (2x2), each wave 64x64 via 4x4 16x16 frags.
// LDS tiles [128 rows][32 bf16] with XOR swizzle sigma(row)=((row>>1)&3)<<4
// applied on both ds_write (staging) and ds_read (fragments) -> conflict-free.
template <bool OUT_BF16>
__global__ __launch_bounds__(256) void gemm_bt(const ushort* __restrict__ A,
                                               const ushort* __restrict__ BT,
                                               void* __restrict__ Cv,
                                               int M, int N, int K) {
  __shared__ __align__(16) char At[128 * 64];
  __shared__ __align__(16) char Bt[128 * 64];
  const int tid = threadIdx.x;
  const int lane = tid & 63, w = tid >> 6;
  const int g = lane >> 4, i = lane & 15;
  const int wr = w >> 1, wc = w & 1;
  const int row0 = blockIdx.x * 128, col0 = blockIdx.y * 128;

  f32x4 acc[4][4] = {};

  for (int k0 = 0; k0 < K; k0 += 32) {
#pragma unroll
    for (int half = 0; half < 2; ++half) {
      int c = tid + half * 256;           // 512 chunks of 16B per 8KB tile
      int r_ = c >> 2, s_ = c & 3;
      int swz = ((r_ >> 1) & 3) << 4;
      uint4 va = *(const uint4*)(A + (size_t)(row0 + r_) * K + k0 + s_ * 8);
      uint4 vb = *(const uint4*)(BT + (size_t)(col0 + r_) * K + k0 + s_ * 8);
      *(uint4*)(At + r_ * 64 + ((s_ * 16) ^ swz)) = va;
      *(uint4*)(Bt + r_ * 64 + ((s_ * 16) ^ swz)) = vb;
    }
    __syncthreads();
    bf16x8 af[4], bf[4];
#pragma unroll
    for (int mi = 0; mi < 4; ++mi) {
      int r_ = wr * 64 + mi * 16 + i;
      af[mi] = *(const bf16x8*)(At + r_ * 64 + ((g * 16) ^ (((r_ >> 1) & 3) << 4)));
    }
#pragma unroll
    for (int ni = 0; ni < 4; ++ni) {
      int r_ = wc * 64 + ni * 16 + i;
      bf[ni] = *(const bf16x8*)(Bt + r_ * 64 + ((g * 16) ^ (((r_ >> 1) & 3) << 4)));
    }
#pragma unroll
    for (int mi = 0; mi < 4; ++mi)
#pragma unroll
      for (int ni = 0; ni < 4; ++ni)
        acc[mi][ni] = __builtin_amdgcn_mfma_f32_16x16x32_bf16(af[mi], bf[ni],
                                                              acc[mi][ni], 0, 0, 0);
    __syncthreads();
  }
  // epilogue: D row = 4*(lane>>4)+reg, col = lane&15 (verified m89/m91 layout)
#pragma unroll
  for (int mi = 0; mi < 4; ++mi)
#pragma unroll
    for (int ni = 0; ni < 4; ++ni) {
      int r_ = row0 + wr * 64 + mi * 16 + g * 4;
      int c_ = col0 + wc * 64 + ni * 16 + i;
#pragma unroll
      for (int r = 0; r < 4; ++r) {
        if (OUT_BF16)
          ((ushort*)Cv)[(size_t)(r_ + r) * N + c_] = f2bf(acc[mi][ni][r]);
        else
          ((float*)Cv)[(size_t)(r_ + r) * N + c_] = acc[mi][ni][r];
      }
    }
}

// ---------------- flash causal GQA attention -------------------------------
// grid (16 q-tiles, 32 heads); block 256 = 4 waves x 32 q-rows; KVBLK = 32.
__global__ __launch_bounds__(256) void attn_fwd(const ushort* __restrict__ QKV,
                                                ushort* __restrict__ AO) {
  __shared__ __align__(16) char Kt[32 * 256];   // [32 kv][128 d] swz ((row&7)<<4)
  __shared__ __align__(16) char Vt[128 * 64];   // [128 d][32 kv] swz ((d>>1)&3)<<4
  __shared__ __align__(16) char Pt[4 * 2048];   // per-wave P [32 q][32 kv]
  const int tid = threadIdx.x;
  const int lane = tid & 63, w = tid >> 6;
  const int g = lane >> 4, i = lane & 15;
  const int qt = blockIdx.x, h = blockIdx.y;
  const int hk = h >> 2;
  const int qb = qt * 128 + w * 32;
  char* Pw = Pt + w * 2048;
  const float scale = 0.08838834764831845f;  // 128^-0.5

  // Q as MFMA A-fragments, held in registers: A[m=lane&15][k=8*(lane>>4)+j]
  bf16x8 qf[2][4];
#pragma unroll
  for (int m = 0; m < 2; ++m)
#pragma unroll
    for (int ks = 0; ks < 4; ++ks)
      qf[m][ks] = *(const bf16x8*)(QKV + (size_t)(qb + m * 16 + i) * EQKV +
                                   h * HDIM + ks * 32 + g * 8);

  f32x4 oa[2][8] = {};
  float m_i[8], l_i[8];
#pragma unroll
  for (int x = 0; x < 8; ++x) { m_i[x] = -3.0e38f; l_i[x] = 0.f; }

  const int nkb = qt * 4 + 4;
  for (int kb = 0; kb < nkb; ++kb) {
    const int kv0 = kb * 32;
    // ---- stage K (swizzled rows) and V (transposed, swizzled) ----
#pragma unroll
    for (int half = 0; half < 2; ++half) {
      int c = tid + half * 256;
      int row = c >> 4, slot = c & 15;
      uint4 kvK = *(const uint4*)(QKV + (size_t)(kv0 + row) * EQKV + 4096 +
                                  hk * HDIM + slot * 8);
      *(uint4*)(Kt + row * 256 + ((slot * 16) ^ ((row & 7) << 4))) = kvK;
      uint4 kvV = *(const uint4*)(QKV + (size_t)(kv0 + row) * EQKV + 5120 +
                                  hk * HDIM + slot * 8);
      const ushort* e = (const ushort*)&kvV;
#pragma unroll
      for (int j = 0; j < 8; ++j) {
        int d = slot * 8 + j;
        *(ushort*)(Vt + d * 64 + ((row * 2) ^ (((d >> 1) & 3) << 4))) = e[j];
      }
    }
    __syncthreads();
    if (kv0 <= qb + 31) {  // wave-uniform causal skip
      // ---- S = Q K^T ----
      f32x4 Sv[2][2] = {};
#pragma unroll
      for (int ks = 0; ks < 4; ++ks)
#pragma unroll
        for (int n = 0; n < 2; ++n) {
          int r_ = n * 16 + i;
          bf16x8 kf = *(const bf16x8*)(Kt + r_ * 256 +
                                       ((ks * 64 + g * 16) ^ ((r_ & 7) << 4)));
#pragma unroll
          for (int m = 0; m < 2; ++m)
            Sv[m][n] = __builtin_amdgcn_mfma_f32_16x16x32_bf16(qf[m][ks], kf,
                                                               Sv[m][n], 0, 0, 0);
        }
      // ---- scale + causal mask ----
      float ps[2][2][4];
      float alpha[8];
#pragma unroll
      for (int m = 0; m < 2; ++m)
#pragma unroll
        for (int r = 0; r < 4; ++r) {
          int q = qb + m * 16 + g * 4 + r;
#pragma unroll
          for (int n = 0; n < 2; ++n) {
            int kv = kv0 + n * 16 + i;
            float s = Sv[m][n][r] * scale;
            ps[m][n][r] = (kv > q) ? -3.0e38f : s;
          }
        }
      // ---- online softmax (row stats across the 16-lane kv groups) ----
#pragma unroll
      for (int m = 0; m < 2; ++m)
#pragma unroll
        for (int r = 0; r < 4; ++r) {
          int idx = m * 4 + r;
          float pm = fmaxf(ps[m][0][r], ps[m][1][r]);
          pm = fmaxf(pm, __shfl_xor(pm, 1));
          pm = fmaxf(pm, __shfl_xor(pm, 2));
          pm = fmaxf(pm, __shfl_xor(pm, 4));
          pm = fmaxf(pm, __shfl_xor(pm, 8));
          float mn = fmaxf(m_i[idx], pm);
          float al = __expf(m_i[idx] - mn);
          float p0 = __expf(ps[m][0][r] - mn);
          float p1 = __expf(ps[m][1][r] - mn);
          float rs = p0 + p1;
          rs += __shfl_xor(rs, 1);
          rs += __shfl_xor(rs, 2);
          rs += __shfl_xor(rs, 4);
          rs += __shfl_xor(rs, 8);
          l_i[idx] = l_i[idx] * al + rs;
          m_i[idx] = mn;
          alpha[idx] = al;
          ps[m][0][r] = p0;
          ps[m][1][r] = p1;
        }
      // ---- rescale O ----
#pragma unroll
      for (int m = 0; m < 2; ++m)
#pragma unroll
        for (int nd = 0; nd < 8; ++nd)
#pragma unroll
          for (int r = 0; r < 4; ++r)
            oa[m][nd][r] *= alpha[m * 4 + r];
      // ---- P: D-layout -> LDS (bf16, swizzled) -> A-fragments ----
#pragma unroll
      for (int m = 0; m < 2; ++m)
#pragma unroll
        for (int n = 0; n < 2; ++n)
#pragma unroll
          for (int r = 0; r < 4; ++r) {
            int row = m * 16 + g * 4 + r;
            int col = n * 16 + i;
            *(ushort*)(Pw + row * 64 + ((col * 2) ^ (((row >> 1) & 3) << 4))) =
                f2bf(ps[m][n][r]);
          }
      bf16x8 pa[2];
#pragma unroll
      for (int m = 0; m < 2; ++m) {
        int row = m * 16 + i;
        pa[m] = *(const bf16x8*)(Pw + row * 64 + ((g * 16) ^ (((row >> 1) & 3) << 4)));
      }
      // ---- O += P V ----
#pragma unroll
      for (int nd = 0; nd < 8; ++nd) {
        int row = nd * 16 + i;
        bf16x8 vf = *(const bf16x8*)(Vt + row * 64 + ((g * 16) ^ (((row >> 1) & 3) << 4)));
#pragma unroll
        for (int m = 0; m < 2; ++m)
          oa[m][nd] = __builtin_amdgcn_mfma_f32_16x16x32_bf16(pa[m], vf,
                                                              oa[m][nd], 0, 0, 0);
      }
    }
    __syncthreads();
  }
  // ---- epilogue: O / l -> AO bf16 [S][4096] ----
#pragma unroll
  for (int m = 0; m < 2; ++m)
#pragma unroll
    for (int nd = 0; nd < 8; ++nd)
#pragma unroll
      for (int r = 0; r < 4; ++r) {
        int q = qb + m * 16 + g * 4 + r;
        int col = h * HDIM + nd * 16 + i;
        AO[(size_t)q * DMODEL + col] = f2bf(oa[m][nd][r] / l_i[m * 4 + r]);
      }
}

// ---------------------------------------------------------------------------
extern "C" void kernel_launch(void* const* d_in, const int* in_sizes, int n_in,
                              void* d_out, int out_size, void* d_ws, size_t ws_size,
                              hipStream_t stream) {
  const float* hidden = (const float*)d_in[1];
  const float* Wqkv   = (const float*)d_in[2];
  const float* Wo     = (const float*)d_in[3];
  float* out = (float*)d_out;

  char* ws = (char*)d_ws;
  // workspace layout (bytes)
  const size_t off_Xb    = 0;                       // 2048*4096*2   = 16 MiB
  const size_t off_QKV   = 16777216;                // 2048*6144*2   = 24 MiB
  const size_t off_AO    = 41943040;                // 2048*4096*2   = 16 MiB
  const size_t off_WqkvT = 58720256;                // 6144*4096*2   = 48 MiB
  const size_t off_WoT   = 109051904;               // 4096*4096*2   = 32 MiB
  ushort* Xb    = (ushort*)(ws + off_Xb);
  ushort* QKVb  = (ushort*)(ws + off_QKV);
  ushort* AO    = (ushort*)(ws + off_AO);
  ushort* WqkvT = (ushort*)(ws + off_WqkvT);
  ushort* WoT   = (ushort*)(ws + off_WoT);

  // 1. convert hidden -> bf16
  cvt_f32_bf16<<<(S_LEN * DMODEL / 4 + 255) / 256, 256, 0, stream>>>(
      hidden, Xb, S_LEN * DMODEL / 4);
  // 2. transpose-convert weights: W [K][N] fp32 -> WT [N][K] bf16
  transpose_cvt<<<dim3(DMODEL / 32, EQKV / 32), 256, 0, stream>>>(Wqkv, WqkvT,
                                                                  DMODEL, EQKV);
  transpose_cvt<<<dim3(DMODEL / 32, DMODEL / 32), 256, 0, stream>>>(Wo, WoT,
                                                                    DMODEL, DMODEL);
  // 3. QKV = X @ Wqkv   (bf16 out)
  gemm_bt<true><<<dim3(S_LEN / 128, EQKV / 128), 256, 0, stream>>>(
      Xb, WqkvT, (void*)QKVb, S_LEN, EQKV, DMODEL);
  // 4. flash causal GQA attention
  attn_fwd<<<dim3(S_LEN / 128, NHEADS), 256, 0, stream>>>(QKVb, AO);
  // 5. out = AO @ Wo    (fp32 out)
  gemm_bt<false><<<dim3(S_LEN / 128, DMODEL / 128), 256, 0, stream>>>(
      AO, WoT, (void*)out, S_LEN, DMODEL, DMODEL);
}

// Round 7
// 583.030 us; speedup vs baseline: 1.4927x; 1.4927x over previous
//
#include <hip/hip_runtime.h>

// ---------------------------------------------------------------------------
// LlamaAttention fused forward on MI355X (gfx950), bf16 MFMA pipeline.
// R7 bisect: R5 still NaN'd => global_load_lds was NOT the cause. Remove the
// two unverified exotic paths from the attention kernel, keep all structure:
//   - v_cvt_pk_bf16_f32 inline asm  -> plain f2bf packing
//   - 16x ds_bpermute P^T relayout  -> per-wave padded LDS P^T buffer
//   - mask constant -3e38 -> -1e30 (exp args finite pre-scale)
// GEMMs keep R1-proven explicit staging + XCD-swizzled grid (bijective).
// ---------------------------------------------------------------------------

#define S_LEN 2048
#define DMODEL 4096
#define EQKV 6144
#define NHEADS 32
#define NKV 8
#define HDIM 128

using bf16x8 = __attribute__((ext_vector_type(8))) short;
using f32x4  = __attribute__((ext_vector_type(4))) float;

__device__ __forceinline__ ushort f2bf(float f) {
  unsigned u = __float_as_uint(f);
  u += 0x7fffu + ((u >> 16) & 1u);   // round-to-nearest-even
  return (ushort)(u >> 16);
}

// ---------------- fp32 -> bf16 elementwise (vectorized) --------------------
__global__ __launch_bounds__(256) void cvt_f32_bf16(const float* __restrict__ in,
                                                    ushort* __restrict__ out, int n4) {
  int idx = blockIdx.x * 256 + threadIdx.x;
  if (idx < n4) {
    float4 v = ((const float4*)in)[idx];
    ushort4 o;
    o.x = f2bf(v.x); o.y = f2bf(v.y); o.z = f2bf(v.z); o.w = f2bf(v.w);
    ((ushort4*)out)[idx] = o;
  }
}

// ---------------- fp32 [K][N] -> bf16 [N][K] tiled transpose ---------------
__global__ __launch_bounds__(256) void transpose_cvt(const float* __restrict__ W,
                                                     ushort* __restrict__ WT,
                                                     int K, int N) {
  __shared__ float t[32][33];
  const int kb = blockIdx.x * 32, nb = blockIdx.y * 32;
  const int tx = threadIdx.x & 31, ty = threadIdx.x >> 5;  // ty 0..7
#pragma unroll
  for (int i = 0; i < 4; ++i)
    t[ty + i * 8][tx] = W[(size_t)(kb + ty + i * 8) * N + nb + tx];
  __syncthreads();
#pragma unroll
  for (int i = 0; i < 4; ++i)
    WT[(size_t)(nb + ty + i * 8) * K + kb + tx] = f2bf(t[tx][ty + i * 8]);
}

// ---------------- bf16 V^T pre-transpose: QKV V cols -> VT[hk][d][s] -------
__global__ __launch_bounds__(256) void vtrans(const ushort* __restrict__ QKV,
                                              ushort* __restrict__ VTg) {
  __shared__ ushort T[64][72];  // pad 72: conflict-free both phases
  const int kv0 = blockIdx.x * 64;
  const int by = blockIdx.y;                 // 0..15
  const int hk = by >> 1, dl0 = (by & 1) * 64;
#pragma unroll
  for (int t = 0; t < 4; ++t) {
    int C = t * 256 + threadIdx.x;
    int r = C >> 4, s = C & 15;
    *(ushort4*)&T[r][s * 4] =
        *(const ushort4*)(QKV + (size_t)(kv0 + r) * EQKV + 5120 + by * 64 + s * 4);
  }
  __syncthreads();
#pragma unroll
  for (int t = 0; t < 4; ++t) {
    int C = t * 256 + threadIdx.x;
    int d = C >> 4, kc = C & 15;
    ushort4 o;
    o.x = T[kc * 4 + 0][d]; o.y = T[kc * 4 + 1][d];
    o.z = T[kc * 4 + 2][d]; o.w = T[kc * 4 + 3][d];
    *(ushort4*)(VTg + (size_t)hk * 262144 + (size_t)(dl0 + d) * 2048 + kv0 + kc * 4) = o;
  }
}

// ---------------- bf16 GEMM: C[M][N] = A[M][K] @ BT[N][K]^T ----------------
// R1-proven staging: 128x128 tile, BK=32, LDS [128 rows][64B] with XOR
// swizzle sigma(row)=((row>>1)&3)<<4 on write AND read. XCD-swizzled grid.
template <bool OUT_BF16>
__global__ __launch_bounds__(256) void gemm_bt(const ushort* __restrict__ A,
                                               const ushort* __restrict__ BT,
                                               void* __restrict__ Cv,
                                               int M, int N, int K, int nbx) {
  __shared__ __align__(16) char At[128 * 64];
  __shared__ __align__(16) char Bt[128 * 64];
  const int tid = threadIdx.x;
  const int lane = tid & 63, w = tid >> 6;
  const int g = lane >> 4, i = lane & 15;
  const int wr = w >> 1, wc = w & 1;
  const int cpx = gridDim.x >> 3;
  const int sw = ((int)blockIdx.x & 7) * cpx + ((int)blockIdx.x >> 3);
  const int row0 = (sw % nbx) * 128, col0 = (sw / nbx) * 128;

  f32x4 acc[4][4] = {};

  for (int k0 = 0; k0 < K; k0 += 32) {
#pragma unroll
    for (int half = 0; half < 2; ++half) {
      int c = tid + half * 256;           // 512 chunks of 16B per 8KB tile
      int r_ = c >> 2, s_ = c & 3;
      int swz = ((r_ >> 1) & 3) << 4;
      uint4 va = *(const uint4*)(A + (size_t)(row0 + r_) * K + k0 + s_ * 8);
      uint4 vb = *(const uint4*)(BT + (size_t)(col0 + r_) * K + k0 + s_ * 8);
      *(uint4*)(At + r_ * 64 + ((s_ * 16) ^ swz)) = va;
      *(uint4*)(Bt + r_ * 64 + ((s_ * 16) ^ swz)) = vb;
    }
    __syncthreads();
    bf16x8 af[4], bfr[4];
#pragma unroll
    for (int mi = 0; mi < 4; ++mi) {
      int r_ = wr * 64 + mi * 16 + i;
      af[mi] = *(const bf16x8*)(At + r_ * 64 + ((g * 16) ^ (((r_ >> 1) & 3) << 4)));
    }
#pragma unroll
    for (int ni = 0; ni < 4; ++ni) {
      int r_ = wc * 64 + ni * 16 + i;
      bfr[ni] = *(const bf16x8*)(Bt + r_ * 64 + ((g * 16) ^ (((r_ >> 1) & 3) << 4)));
    }
#pragma unroll
    for (int mi = 0; mi < 4; ++mi)
#pragma unroll
      for (int ni = 0; ni < 4; ++ni)
        acc[mi][ni] = __builtin_amdgcn_mfma_f32_16x16x32_bf16(af[mi], bfr[ni],
                                                              acc[mi][ni], 0, 0, 0);
    __syncthreads();
  }
  // epilogue: D row = 4*(lane>>4)+reg, col = lane&15 (verified m89/m91 layout)
#pragma unroll
  for (int mi = 0; mi < 4; ++mi)
#pragma unroll
    for (int ni = 0; ni < 4; ++ni) {
      int r_ = row0 + wr * 64 + mi * 16 + g * 4;
      int c_ = col0 + wc * 64 + ni * 16 + i;
#pragma unroll
      for (int r = 0; r < 4; ++r) {
        if (OUT_BF16)
          ((ushort*)Cv)[(size_t)(r_ + r) * N + c_] = f2bf(acc[mi][ni][r]);
        else
          ((float*)Cv)[(size_t)(r_ + r) * N + c_] = acc[mi][ni][r];
      }
    }
}

// ---------------- flash causal GQA attention (swapped-operand) -------------
// 512 blocks (1D): hk = b&7 (XCD-pinned), heavy qt first. 4 waves x 32 q.
// KVBLK=64. S^T = K·Q^T; softmax per q-column (2 shfls); P^T via per-wave
// padded LDS buffer; O^T += V^T·P^T; epilogue transposes O via LDS bounce.
__global__ __launch_bounds__(256) void attn_fwd(const ushort* __restrict__ QKV,
                                                const ushort* __restrict__ VTg,
                                                ushort* __restrict__ AO) {
  __shared__ __align__(16) char smem[32768];
  __shared__ ushort Pt[4][64 * 33];   // per-wave P^T [64 kv][32 q], stride 33
  char* Ks = smem;            // [64 kv][256B], swz ((row&7)<<4)
  char* Vs = smem + 16384;    // [128 d][128B], swz ((d&7)<<4)
  const int tid = threadIdx.x;
  const int lane = tid & 63, w = tid >> 6;
  const int g = lane >> 4, i = lane & 15;

  const int b = blockIdx.x;
  const int hk = b & 7;
  const int idx = b >> 3;                 // 0..63
  const int h = hk * 4 + (idx & 3);
  const int qt = 15 - (idx >> 2);         // heavy-first
  const int qb = qt * 128 + w * 32;
  const float scale = 0.08838834764831845f;  // 128^-0.5
  const float NEGINF = -1.0e30f;

  const ushort* Kg = QKV + 4096 + hk * HDIM;
  const ushort* Vg = VTg + (size_t)hk * 262144;
  ushort* Pw = Pt[w];

  // Q^T B-frags in registers: lane (g,i) holds Q[qb+nt*16+i][ks*32+g*8+j]
  bf16x8 qf[2][4];
#pragma unroll
  for (int nt = 0; nt < 2; ++nt)
#pragma unroll
    for (int ks = 0; ks < 4; ++ks)
      qf[nt][ks] = *(const bf16x8*)(QKV + (size_t)(qb + nt * 16 + i) * EQKV +
                                    h * HDIM + ks * 32 + g * 8);

  f32x4 ot[8][2] = {};           // O^T frags: [d-tile][q-tile]
  float m_i[2] = {-1.0e30f, -1.0e30f}, l_i[2] = {0.f, 0.f};

  const int nkb = (qt + 1) * 2;  // kv64 blocks up to diagonal of the block
  for (int kb = 0; kb < nkb; ++kb) {
    const int kv0 = kb * 64;
    // ---- stage K [64][128] and V^T [128][64], both vectorized + swizzled --
#pragma unroll
    for (int t = 0; t < 4; ++t) {
      int C = t * 256 + tid;
      int row = C >> 4, slot = C & 15;
      uint4 kv = *(const uint4*)(Kg + (size_t)(kv0 + row) * EQKV + slot * 8);
      *(uint4*)(Ks + row * 256 + ((slot * 16) ^ ((row & 7) << 4))) = kv;
      int d = C >> 3, sl = C & 7;
      uint4 vv = *(const uint4*)(Vg + (size_t)d * 2048 + kv0 + sl * 8);
      *(uint4*)(Vs + d * 128 + ((sl * 16) ^ ((d & 7) << 4))) = vv;
    }
    __syncthreads();
    if (kv0 <= qb + 31) {   // wave-uniform causal skip
      // ---- S^T = K Q^T : rows kv (4 m-tiles), cols q (2 n-tiles) ----
      f32x4 st[4][2] = {};
#pragma unroll
      for (int ks = 0; ks < 4; ++ks)
#pragma unroll
        for (int mt = 0; mt < 4; ++mt) {
          int row = mt * 16 + i;
          bf16x8 kf = *(const bf16x8*)(Ks + row * 256 +
                                       ((ks * 64 + g * 16) ^ ((row & 7) << 4)));
#pragma unroll
          for (int nt = 0; nt < 2; ++nt)
            st[mt][nt] = __builtin_amdgcn_mfma_f32_16x16x32_bf16(kf, qf[nt][ks],
                                                                 st[mt][nt], 0, 0, 0);
        }
      // ---- per-q-column online softmax (lane holds 16 of 64 kv) ----
      float al[2];
#pragma unroll
      for (int nt = 0; nt < 2; ++nt) {
        const int qg = qb + nt * 16 + i;
        float ps[4][4];
        float tm = NEGINF;
#pragma unroll
        for (int mt = 0; mt < 4; ++mt)
#pragma unroll
          for (int r = 0; r < 4; ++r) {
            int kvg = kv0 + mt * 16 + g * 4 + r;
            float s = st[mt][nt][r] * scale;
            s = (kvg > qg) ? NEGINF : s;
            ps[mt][r] = s;
            tm = fmaxf(tm, s);
          }
        tm = fmaxf(tm, __shfl_xor(tm, 16));
        tm = fmaxf(tm, __shfl_xor(tm, 32));
        float mn = fmaxf(m_i[nt], tm);
        float a = __expf(m_i[nt] - mn);
        float rs = 0.f;
#pragma unroll
        for (int mt = 0; mt < 4; ++mt)
#pragma unroll
          for (int r = 0; r < 4; ++r) {
            ps[mt][r] = __expf(ps[mt][r] - mn);
            rs += ps[mt][r];
          }
        rs += __shfl_xor(rs, 16);
        rs += __shfl_xor(rs, 32);
        l_i[nt] = l_i[nt] * a + rs;
        m_i[nt] = mn;
        al[nt] = a;
        // ---- P^T (D-layout) -> per-wave LDS buffer, bf16 ----
#pragma unroll
        for (int mt = 0; mt < 4; ++mt)
#pragma unroll
          for (int r = 0; r < 4; ++r)
            Pw[(mt * 16 + g * 4 + r) * 33 + nt * 16 + i] = f2bf(ps[mt][r]);
      }
      // ---- rescale O^T ----
#pragma unroll
      for (int md = 0; md < 8; ++md)
#pragma unroll
        for (int nt = 0; nt < 2; ++nt)
#pragma unroll
          for (int r = 0; r < 4; ++r)
            ot[md][nt][r] *= al[nt];
      // ---- P^T B-frags from LDS (same-wave RAW, no barrier needed) ----
      bf16x8 ptf[2][2];
#pragma unroll
      for (int kst = 0; kst < 2; ++kst)
#pragma unroll
        for (int nt = 0; nt < 2; ++nt) {
          union { ushort e[8]; bf16x8 v; } uu;
#pragma unroll
          for (int j = 0; j < 8; ++j)
            uu.e[j] = Pw[(kst * 32 + g * 8 + j) * 33 + nt * 16 + i];
          ptf[kst][nt] = uu.v;
        }
      // ---- O^T += V^T P^T ----
#pragma unroll
      for (int md = 0; md < 8; ++md)
#pragma unroll
        for (int kst = 0; kst < 2; ++kst) {
          int row = md * 16 + i;
          bf16x8 vf = *(const bf16x8*)(Vs + row * 128 +
                                       ((kst * 64 + g * 16) ^ ((row & 7) << 4)));
#pragma unroll
          for (int nt = 0; nt < 2; ++nt)
            ot[md][nt] = __builtin_amdgcn_mfma_f32_16x16x32_bf16(vf, ptf[kst][nt],
                                                                 ot[md][nt], 0, 0, 0);
        }
    }
    __syncthreads();
  }
  // ---- epilogue: O^T/l -> per-wave LDS bounce -> coalesced AO stores ----
  char* Sw = smem + w * 8192;   // [32 q][256B] swz ((q&7)<<4)
#pragma unroll
  for (int md = 0; md < 8; ++md)
#pragma unroll
    for (int nt = 0; nt < 2; ++nt)
#pragma unroll
      for (int r = 0; r < 4; ++r) {
        int row = nt * 16 + i, col = md * 16 + g * 4 + r;
        *(ushort*)(Sw + row * 256 + ((col * 2) ^ ((row & 7) << 4))) =
            f2bf(ot[md][nt][r] / l_i[nt]);
      }
#pragma unroll
  for (int t = 0; t < 8; ++t) {
    int c = t * 64 + lane;
    int row = c >> 4, sl = c & 15;
    uint4 v = *(const uint4*)(Sw + row * 256 + ((sl * 16) ^ ((row & 7) << 4)));
    *(uint4*)(AO + (size_t)(qb + row) * DMODEL + h * HDIM + sl * 8) = v;
  }
}

// ---------------------------------------------------------------------------
extern "C" void kernel_launch(void* const* d_in, const int* in_sizes, int n_in,
                              void* d_out, int out_size, void* d_ws, size_t ws_size,
                              hipStream_t stream) {
  const float* hidden = (const float*)d_in[1];
  const float* Wqkv   = (const float*)d_in[2];
  const float* Wo     = (const float*)d_in[3];
  float* out = (float*)d_out;

  char* ws = (char*)d_ws;
  // workspace layout (bytes)
  const size_t off_Xb    = 0;                       // 16 MiB (VTg overlays after gemm1)
  const size_t off_QKV   = 16777216;                // 24 MiB
  const size_t off_AO    = 41943040;                // 16 MiB
  const size_t off_WqkvT = 58720256;                // 48 MiB
  const size_t off_WoT   = 109051904;               // 32 MiB
  ushort* Xb    = (ushort*)(ws + off_Xb);
  ushort* VTg   = (ushort*)(ws + off_Xb);           // reuse: 4 MiB, after gemm1
  ushort* QKVb  = (ushort*)(ws + off_QKV);
  ushort* AO    = (ushort*)(ws + off_AO);
  ushort* WqkvT = (ushort*)(ws + off_WqkvT);
  ushort* WoT   = (ushort*)(ws + off_WoT);

  // 1. convert hidden -> bf16
  cvt_f32_bf16<<<(S_LEN * DMODEL / 4 + 255) / 256, 256, 0, stream>>>(
      hidden, Xb, S_LEN * DMODEL / 4);
  // 2. transpose-convert weights: W [K][N] fp32 -> WT [N][K] bf16
  transpose_cvt<<<dim3(DMODEL / 32, EQKV / 32), 256, 0, stream>>>(Wqkv, WqkvT,
                                                                  DMODEL, EQKV);
  transpose_cvt<<<dim3(DMODEL / 32, DMODEL / 32), 256, 0, stream>>>(Wo, WoT,
                                                                    DMODEL, DMODEL);
  // 3. QKV = X @ Wqkv   (bf16 out)
  gemm_bt<true><<<768, 256, 0, stream>>>(Xb, WqkvT, (void*)QKVb,
                                         S_LEN, EQKV, DMODEL, 16);
  // 4. V^T pre-transpose (4 MiB, overlays Xb)
  vtrans<<<dim3(32, 16), 256, 0, stream>>>(QKVb, VTg);
  // 5. flash causal GQA attention
  attn_fwd<<<512, 256, 0, stream>>>(QKVb, VTg, AO);
  // 6. out = AO @ Wo    (fp32 out)
  gemm_bt<false><<<512, 256, 0, stream>>>(AO, WoT, (void*)out,
                                          S_LEN, DMODEL, DMODEL, 16);
}

// Round 8
// 581.103 us; speedup vs baseline: 1.4976x; 1.0033x over previous
//
#include <hip/hip_runtime.h>

// ---------------------------------------------------------------------------
// LlamaAttention fused forward on MI355X (gfx950), bf16 MFMA pipeline.
// R8: single-variable upgrade over R7-passing baseline:
//   gemm_bt -> m97 structure (global_load_lds width-16, linear LDS [128][32]).
//   Attention / transposes / vtrans byte-identical to R7 (passed, 583 us).
// If this NaNs, global_load_lds usage is definitively the fault (clean A/B).
// ---------------------------------------------------------------------------

#define S_LEN 2048
#define DMODEL 4096
#define EQKV 6144
#define NHEADS 32
#define NKV 8
#define HDIM 128

using bf16x8 = __attribute__((ext_vector_type(8))) short;
using f32x4  = __attribute__((ext_vector_type(4))) float;

__device__ __forceinline__ ushort f2bf(float f) {
  unsigned u = __float_as_uint(f);
  u += 0x7fffu + ((u >> 16) & 1u);   // round-to-nearest-even
  return (ushort)(u >> 16);
}

// async global->LDS, 16B per lane; lds base must be wave-uniform
__device__ __forceinline__ void gll16(const void* g, void* l) {
  __builtin_amdgcn_global_load_lds(
      (const __attribute__((address_space(1))) unsigned int*)g,
      (__attribute__((address_space(3))) unsigned int*)l, 16, 0, 0);
}

// ---------------- fp32 -> bf16 elementwise (vectorized) --------------------
__global__ __launch_bounds__(256) void cvt_f32_bf16(const float* __restrict__ in,
                                                    ushort* __restrict__ out, int n4) {
  int idx = blockIdx.x * 256 + threadIdx.x;
  if (idx < n4) {
    float4 v = ((const float4*)in)[idx];
    ushort4 o;
    o.x = f2bf(v.x); o.y = f2bf(v.y); o.z = f2bf(v.z); o.w = f2bf(v.w);
    ((ushort4*)out)[idx] = o;
  }
}

// ---------------- fp32 [K][N] -> bf16 [N][K] tiled transpose ---------------
__global__ __launch_bounds__(256) void transpose_cvt(const float* __restrict__ W,
                                                     ushort* __restrict__ WT,
                                                     int K, int N) {
  __shared__ float t[32][33];
  const int kb = blockIdx.x * 32, nb = blockIdx.y * 32;
  const int tx = threadIdx.x & 31, ty = threadIdx.x >> 5;  // ty 0..7
#pragma unroll
  for (int i = 0; i < 4; ++i)
    t[ty + i * 8][tx] = W[(size_t)(kb + ty + i * 8) * N + nb + tx];
  __syncthreads();
#pragma unroll
  for (int i = 0; i < 4; ++i)
    WT[(size_t)(nb + ty + i * 8) * K + kb + tx] = f2bf(t[tx][ty + i * 8]);
}

// ---------------- bf16 V^T pre-transpose: QKV V cols -> VT[hk][d][s] -------
__global__ __launch_bounds__(256) void vtrans(const ushort* __restrict__ QKV,
                                              ushort* __restrict__ VTg) {
  __shared__ ushort T[64][72];  // pad 72: conflict-free both phases
  const int kv0 = blockIdx.x * 64;
  const int by = blockIdx.y;                 // 0..15
  const int hk = by >> 1, dl0 = (by & 1) * 64;
#pragma unroll
  for (int t = 0; t < 4; ++t) {
    int C = t * 256 + threadIdx.x;
    int r = C >> 4, s = C & 15;
    *(ushort4*)&T[r][s * 4] =
        *(const ushort4*)(QKV + (size_t)(kv0 + r) * EQKV + 5120 + by * 64 + s * 4);
  }
  __syncthreads();
#pragma unroll
  for (int t = 0; t < 4; ++t) {
    int C = t * 256 + threadIdx.x;
    int d = C >> 4, kc = C & 15;
    ushort4 o;
    o.x = T[kc * 4 + 0][d]; o.y = T[kc * 4 + 1][d];
    o.z = T[kc * 4 + 2][d]; o.w = T[kc * 4 + 3][d];
    *(ushort4*)(VTg + (size_t)hk * 262144 + (size_t)(dl0 + d) * 2048 + kv0 + kc * 4) = o;
  }
}

// ---------------- bf16 GEMM (m97 structure): C = A @ BT^T ------------------
// 128x128 tile, BK=32, linear LDS [128][32], global_load_lds width-16,
// 4 waves (2x2), 4x4 16x16x32 frags per wave. XCD-swizzled 1D grid.
template <bool OUT_BF16>
__global__ __launch_bounds__(256) void gemm_bt(const ushort* __restrict__ A,
                                               const ushort* __restrict__ BT,
                                               void* __restrict__ Cv,
                                               int M, int N, int K, int nbx) {
  __shared__ __align__(16) ushort At[4096];
  __shared__ __align__(16) ushort Bt[4096];
  const int tid = threadIdx.x;
  const int lane = tid & 63, w = tid >> 6;
  const int g = lane >> 4, i = lane & 15;
  const int wr = w >> 1, wc = w & 1;
  const int cpx = gridDim.x >> 3;
  const int sw = ((int)blockIdx.x & 7) * cpx + ((int)blockIdx.x >> 3);
  const int row0 = (sw % nbx) * 128, col0 = (sw / nbx) * 128;

  f32x4 acc[4][4] = {};

  for (int k0 = 0; k0 < K; k0 += 32) {
#pragma unroll
    for (int t = 0; t < 2; ++t) {
      int c = (w * 2 + t) * 64 + lane;   // 16B chunk index, 0..511
      int r = c >> 2, s = c & 3;
      gll16(A + (size_t)(row0 + r) * K + k0 + s * 8, At + (w * 2 + t) * 512);
      gll16(BT + (size_t)(col0 + r) * K + k0 + s * 8, Bt + (w * 2 + t) * 512);
    }
    __syncthreads();
    bf16x8 af[4], bfr[4];
#pragma unroll
    for (int mi = 0; mi < 4; ++mi)
      af[mi] = *(const bf16x8*)(At + (wr * 64 + mi * 16 + i) * 32 + g * 8);
#pragma unroll
    for (int ni = 0; ni < 4; ++ni)
      bfr[ni] = *(const bf16x8*)(Bt + (wc * 64 + ni * 16 + i) * 32 + g * 8);
#pragma unroll
    for (int mi = 0; mi < 4; ++mi)
#pragma unroll
      for (int ni = 0; ni < 4; ++ni)
        acc[mi][ni] = __builtin_amdgcn_mfma_f32_16x16x32_bf16(af[mi], bfr[ni],
                                                              acc[mi][ni], 0, 0, 0);
    __syncthreads();
  }
  // epilogue: D row = 4*(lane>>4)+reg, col = lane&15 (verified m89/m91 layout)
#pragma unroll
  for (int mi = 0; mi < 4; ++mi)
#pragma unroll
    for (int ni = 0; ni < 4; ++ni) {
      int r_ = row0 + wr * 64 + mi * 16 + g * 4;
      int c_ = col0 + wc * 64 + ni * 16 + i;
#pragma unroll
      for (int r = 0; r < 4; ++r) {
        if (OUT_BF16)
          ((ushort*)Cv)[(size_t)(r_ + r) * N + c_] = f2bf(acc[mi][ni][r]);
        else
          ((float*)Cv)[(size_t)(r_ + r) * N + c_] = acc[mi][ni][r];
      }
    }
}

// ---------------- flash causal GQA attention (swapped-operand) -------------
// Byte-identical to R7 (passed): 512 blocks, hk=b&7 XCD-pinned, heavy-first.
// KVBLK=64. S^T = K·Q^T; softmax per q-column (2 shfls); P^T via per-wave
// padded LDS buffer; O^T += V^T·P^T; epilogue transposes O via LDS bounce.
__global__ __launch_bounds__(256) void attn_fwd(const ushort* __restrict__ QKV,
                                                const ushort* __restrict__ VTg,
                                                ushort* __restrict__ AO) {
  __shared__ __align__(16) char smem[32768];
  __shared__ ushort Pt[4][64 * 33];   // per-wave P^T [64 kv][32 q], stride 33
  char* Ks = smem;            // [64 kv][256B], swz ((row&7)<<4)
  char* Vs = smem + 16384;    // [128 d][128B], swz ((d&7)<<4)
  const int tid = threadIdx.x;
  const int lane = tid & 63, w = tid >> 6;
  const int g = lane >> 4, i = lane & 15;

  const int b = blockIdx.x;
  const int hk = b & 7;
  const int idx = b >> 3;                 // 0..63
  const int h = hk * 4 + (idx & 3);
  const int qt = 15 - (idx >> 2);         // heavy-first
  const int qb = qt * 128 + w * 32;
  const float scale = 0.08838834764831845f;  // 128^-0.5
  const float NEGINF = -1.0e30f;

  const ushort* Kg = QKV + 4096 + hk * HDIM;
  const ushort* Vg = VTg + (size_t)hk * 262144;
  ushort* Pw = Pt[w];

  // Q^T B-frags in registers: lane (g,i) holds Q[qb+nt*16+i][ks*32+g*8+j]
  bf16x8 qf[2][4];
#pragma unroll
  for (int nt = 0; nt < 2; ++nt)
#pragma unroll
    for (int ks = 0; ks < 4; ++ks)
      qf[nt][ks] = *(const bf16x8*)(QKV + (size_t)(qb + nt * 16 + i) * EQKV +
                                    h * HDIM + ks * 32 + g * 8);

  f32x4 ot[8][2] = {};           // O^T frags: [d-tile][q-tile]
  float m_i[2] = {-1.0e30f, -1.0e30f}, l_i[2] = {0.f, 0.f};

  const int nkb = (qt + 1) * 2;  // kv64 blocks up to diagonal of the block
  for (int kb = 0; kb < nkb; ++kb) {
    const int kv0 = kb * 64;
    // ---- stage K [64][128] and V^T [128][64], both vectorized + swizzled --
#pragma unroll
    for (int t = 0; t < 4; ++t) {
      int C = t * 256 + tid;
      int row = C >> 4, slot = C & 15;
      uint4 kv = *(const uint4*)(Kg + (size_t)(kv0 + row) * EQKV + slot * 8);
      *(uint4*)(Ks + row * 256 + ((slot * 16) ^ ((row & 7) << 4))) = kv;
      int d = C >> 3, sl = C & 7;
      uint4 vv = *(const uint4*)(Vg + (size_t)d * 2048 + kv0 + sl * 8);
      *(uint4*)(Vs + d * 128 + ((sl * 16) ^ ((d & 7) << 4))) = vv;
    }
    __syncthreads();
    if (kv0 <= qb + 31) {   // wave-uniform causal skip
      // ---- S^T = K Q^T : rows kv (4 m-tiles), cols q (2 n-tiles) ----
      f32x4 st[4][2] = {};
#pragma unroll
      for (int ks = 0; ks < 4; ++ks)
#pragma unroll
        for (int mt = 0; mt < 4; ++mt) {
          int row = mt * 16 + i;
          bf16x8 kf = *(const bf16x8*)(Ks + row * 256 +
                                       ((ks * 64 + g * 16) ^ ((row & 7) << 4)));
#pragma unroll
          for (int nt = 0; nt < 2; ++nt)
            st[mt][nt] = __builtin_amdgcn_mfma_f32_16x16x32_bf16(kf, qf[nt][ks],
                                                                 st[mt][nt], 0, 0, 0);
        }
      // ---- per-q-column online softmax (lane holds 16 of 64 kv) ----
      float al[2];
#pragma unroll
      for (int nt = 0; nt < 2; ++nt) {
        const int qg = qb + nt * 16 + i;
        float ps[4][4];
        float tm = NEGINF;
#pragma unroll
        for (int mt = 0; mt < 4; ++mt)
#pragma unroll
          for (int r = 0; r < 4; ++r) {
            int kvg = kv0 + mt * 16 + g * 4 + r;
            float s = st[mt][nt][r] * scale;
            s = (kvg > qg) ? NEGINF : s;
            ps[mt][r] = s;
            tm = fmaxf(tm, s);
          }
        tm = fmaxf(tm, __shfl_xor(tm, 16));
        tm = fmaxf(tm, __shfl_xor(tm, 32));
        float mn = fmaxf(m_i[nt], tm);
        float a = __expf(m_i[nt] - mn);
        float rs = 0.f;
#pragma unroll
        for (int mt = 0; mt < 4; ++mt)
#pragma unroll
          for (int r = 0; r < 4; ++r) {
            ps[mt][r] = __expf(ps[mt][r] - mn);
            rs += ps[mt][r];
          }
        rs += __shfl_xor(rs, 16);
        rs += __shfl_xor(rs, 32);
        l_i[nt] = l_i[nt] * a + rs;
        m_i[nt] = mn;
        al[nt] = a;
        // ---- P^T (D-layout) -> per-wave LDS buffer, bf16 ----
#pragma unroll
        for (int mt = 0; mt < 4; ++mt)
#pragma unroll
          for (int r = 0; r < 4; ++r)
            Pw[(mt * 16 + g * 4 + r) * 33 + nt * 16 + i] = f2bf(ps[mt][r]);
      }
      // ---- rescale O^T ----
#pragma unroll
      for (int md = 0; md < 8; ++md)
#pragma unroll
        for (int nt = 0; nt < 2; ++nt)
#pragma unroll
          for (int r = 0; r < 4; ++r)
            ot[md][nt][r] *= al[nt];
      // ---- P^T B-frags from LDS (same-wave RAW, no barrier needed) ----
      bf16x8 ptf[2][2];
#pragma unroll
      for (int kst = 0; kst < 2; ++kst)
#pragma unroll
        for (int nt = 0; nt < 2; ++nt) {
          union { ushort e[8]; bf16x8 v; } uu;
#pragma unroll
          for (int j = 0; j < 8; ++j)
            uu.e[j] = Pw[(kst * 32 + g * 8 + j) * 33 + nt * 16 + i];
          ptf[kst][nt] = uu.v;
        }
      // ---- O^T += V^T P^T ----
#pragma unroll
      for (int md = 0; md < 8; ++md)
#pragma unroll
        for (int kst = 0; kst < 2; ++kst) {
          int row = md * 16 + i;
          bf16x8 vf = *(const bf16x8*)(Vs + row * 128 +
                                       ((kst * 64 + g * 16) ^ ((row & 7) << 4)));
#pragma unroll
          for (int nt = 0; nt < 2; ++nt)
            ot[md][nt] = __builtin_amdgcn_mfma_f32_16x16x32_bf16(vf, ptf[kst][nt],
                                                                 ot[md][nt], 0, 0, 0);
        }
    }
    __syncthreads();
  }
  // ---- epilogue: O^T/l -> per-wave LDS bounce -> coalesced AO stores ----
  char* Sw = smem + w * 8192;   // [32 q][256B] swz ((q&7)<<4)
#pragma unroll
  for (int md = 0; md < 8; ++md)
#pragma unroll
    for (int nt = 0; nt < 2; ++nt)
#pragma unroll
      for (int r = 0; r < 4; ++r) {
        int row = nt * 16 + i, col = md * 16 + g * 4 + r;
        *(ushort*)(Sw + row * 256 + ((col * 2) ^ ((row & 7) << 4))) =
            f2bf(ot[md][nt][r] / l_i[nt]);
      }
#pragma unroll
  for (int t = 0; t < 8; ++t) {
    int c = t * 64 + lane;
    int row = c >> 4, sl = c & 15;
    uint4 v = *(const uint4*)(Sw + row * 256 + ((sl * 16) ^ ((row & 7) << 4)));
    *(uint4*)(AO + (size_t)(qb + row) * DMODEL + h * HDIM + sl * 8) = v;
  }
}

// ---------------------------------------------------------------------------
extern "C" void kernel_launch(void* const* d_in, const int* in_sizes, int n_in,
                              void* d_out, int out_size, void* d_ws, size_t ws_size,
                              hipStream_t stream) {
  const float* hidden = (const float*)d_in[1];
  const float* Wqkv   = (const float*)d_in[2];
  const float* Wo     = (const float*)d_in[3];
  float* out = (float*)d_out;

  char* ws = (char*)d_ws;
  // workspace layout (bytes)
  const size_t off_Xb    = 0;                       // 16 MiB (VTg overlays after gemm1)
  const size_t off_QKV   = 16777216;                // 24 MiB
  const size_t off_AO    = 41943040;                // 16 MiB
  const size_t off_WqkvT = 58720256;                // 48 MiB
  const size_t off_WoT   = 109051904;               // 32 MiB
  ushort* Xb    = (ushort*)(ws + off_Xb);
  ushort* VTg   = (ushort*)(ws + off_Xb);           // reuse: 4 MiB, after gemm1
  ushort* QKVb  = (ushort*)(ws + off_QKV);
  ushort* AO    = (ushort*)(ws + off_AO);
  ushort* WqkvT = (ushort*)(ws + off_WqkvT);
  ushort* WoT   = (ushort*)(ws + off_WoT);

  // 1. convert hidden -> bf16
  cvt_f32_bf16<<<(S_LEN * DMODEL / 4 + 255) / 256, 256, 0, stream>>>(
      hidden, Xb, S_LEN * DMODEL / 4);
  // 2. transpose-convert weights: W [K][N] fp32 -> WT [N][K] bf16
  transpose_cvt<<<dim3(DMODEL / 32, EQKV / 32), 256, 0, stream>>>(Wqkv, WqkvT,
                                                                  DMODEL, EQKV);
  transpose_cvt<<<dim3(DMODEL / 32, DMODEL / 32), 256, 0, stream>>>(Wo, WoT,
                                                                    DMODEL, DMODEL);
  // 3. QKV = X @ Wqkv   (bf16 out)
  gemm_bt<true><<<768, 256, 0, stream>>>(Xb, WqkvT, (void*)QKVb,
                                         S_LEN, EQKV, DMODEL, 16);
  // 4. V^T pre-transpose (4 MiB, overlays Xb)
  vtrans<<<dim3(32, 16), 256, 0, stream>>>(QKVb, VTg);
  // 5. flash causal GQA attention
  attn_fwd<<<512, 256, 0, stream>>>(QKVb, VTg, AO);
  // 6. out = AO @ Wo    (fp32 out)
  gemm_bt<false><<<512, 256, 0, stream>>>(AO, WoT, (void*)out,
                                          S_LEN, DMODEL, DMODEL, 16);
}

// Round 9
// 521.082 us; speedup vs baseline: 1.6701x; 1.1152x over previous
//
#include <hip/hip_runtime.h>

// ---------------------------------------------------------------------------
// LlamaAttention fused forward on MI355X (gfx950), bf16 MFMA pipeline.
// R9: two independent-kernel upgrades over R8 (passed, 581 us):
//  - gemm_bt: BK=64 (half the barrier drains) + both-sides slot XOR-swizzle
//    (pre-swizzled gll16 SOURCE + swizzled ds_read, per rule #21).
//  - attn_fwd: P bounce buffer q-major [32][72]: ushort4 writes + b128 reads
//    (was 64x ds_write_b16 + 32x ds_read_u16 per kv-block).
// Everything else byte-identical to R8.
// ---------------------------------------------------------------------------

#define S_LEN 2048
#define DMODEL 4096
#define EQKV 6144
#define NHEADS 32
#define NKV 8
#define HDIM 128

using bf16x8 = __attribute__((ext_vector_type(8))) short;
using f32x4  = __attribute__((ext_vector_type(4))) float;

__device__ __forceinline__ ushort f2bf(float f) {
  unsigned u = __float_as_uint(f);
  u += 0x7fffu + ((u >> 16) & 1u);   // round-to-nearest-even
  return (ushort)(u >> 16);
}

// async global->LDS, 16B per lane; lds base must be wave-uniform
__device__ __forceinline__ void gll16(const void* g, void* l) {
  __builtin_amdgcn_global_load_lds(
      (const __attribute__((address_space(1))) unsigned int*)g,
      (__attribute__((address_space(3))) unsigned int*)l, 16, 0, 0);
}

// ---------------- fp32 -> bf16 elementwise (vectorized) --------------------
__global__ __launch_bounds__(256) void cvt_f32_bf16(const float* __restrict__ in,
                                                    ushort* __restrict__ out, int n4) {
  int idx = blockIdx.x * 256 + threadIdx.x;
  if (idx < n4) {
    float4 v = ((const float4*)in)[idx];
    ushort4 o;
    o.x = f2bf(v.x); o.y = f2bf(v.y); o.z = f2bf(v.z); o.w = f2bf(v.w);
    ((ushort4*)out)[idx] = o;
  }
}

// ---------------- fp32 [K][N] -> bf16 [N][K] tiled transpose ---------------
__global__ __launch_bounds__(256) void transpose_cvt(const float* __restrict__ W,
                                                     ushort* __restrict__ WT,
                                                     int K, int N) {
  __shared__ float t[32][33];
  const int kb = blockIdx.x * 32, nb = blockIdx.y * 32;
  const int tx = threadIdx.x & 31, ty = threadIdx.x >> 5;  // ty 0..7
#pragma unroll
  for (int i = 0; i < 4; ++i)
    t[ty + i * 8][tx] = W[(size_t)(kb + ty + i * 8) * N + nb + tx];
  __syncthreads();
#pragma unroll
  for (int i = 0; i < 4; ++i)
    WT[(size_t)(nb + ty + i * 8) * K + kb + tx] = f2bf(t[tx][ty + i * 8]);
}

// ---------------- bf16 V^T pre-transpose: QKV V cols -> VT[hk][d][s] -------
__global__ __launch_bounds__(256) void vtrans(const ushort* __restrict__ QKV,
                                              ushort* __restrict__ VTg) {
  __shared__ ushort T[64][72];  // pad 72: conflict-free both phases
  const int kv0 = blockIdx.x * 64;
  const int by = blockIdx.y;                 // 0..15
  const int hk = by >> 1, dl0 = (by & 1) * 64;
#pragma unroll
  for (int t = 0; t < 4; ++t) {
    int C = t * 256 + threadIdx.x;
    int r = C >> 4, s = C & 15;
    *(ushort4*)&T[r][s * 4] =
        *(const ushort4*)(QKV + (size_t)(kv0 + r) * EQKV + 5120 + by * 64 + s * 4);
  }
  __syncthreads();
#pragma unroll
  for (int t = 0; t < 4; ++t) {
    int C = t * 256 + threadIdx.x;
    int d = C >> 4, kc = C & 15;
    ushort4 o;
    o.x = T[kc * 4 + 0][d]; o.y = T[kc * 4 + 1][d];
    o.z = T[kc * 4 + 2][d]; o.w = T[kc * 4 + 3][d];
    *(ushort4*)(VTg + (size_t)hk * 262144 + (size_t)(dl0 + d) * 2048 + kv0 + kc * 4) = o;
  }
}

// ---------------- bf16 GEMM: C = A @ BT^T, BK=64 + slot swizzle ------------
// 128x128 tile, BK=64, LDS [128 rows][128B] linear-dest gll16 with
// pre-swizzled SOURCE slot (s ^= r&7); reads XOR the same -> ~2-way banks.
// 4 waves (2x2), per kk-half: 4+4 frags, 16 MFMA; 32 MFMA per barrier pair.
template <bool OUT_BF16>
__global__ __launch_bounds__(256) void gemm_bt(const ushort* __restrict__ A,
                                               const ushort* __restrict__ BT,
                                               void* __restrict__ Cv,
                                               int M, int N, int K, int nbx) {
  __shared__ __align__(16) ushort At[128 * 64];   // 16 KB
  __shared__ __align__(16) ushort Bt[128 * 64];   // 16 KB
  const int tid = threadIdx.x;
  const int lane = tid & 63, w = tid >> 6;
  const int g = lane >> 4, i = lane & 15;
  const int wr = w >> 1, wc = w & 1;
  const int cpx = gridDim.x >> 3;
  const int sw = ((int)blockIdx.x & 7) * cpx + ((int)blockIdx.x >> 3);
  const int row0 = (sw % nbx) * 128, col0 = (sw / nbx) * 128;

  f32x4 acc[4][4] = {};

  for (int k0 = 0; k0 < K; k0 += 64) {
#pragma unroll
    for (int t = 0; t < 4; ++t) {
      int c = (w * 4 + t) * 64 + lane;     // 16B chunk index, 0..1023
      int r = c >> 3, s = c & 7;           // row 0..127, slot 0..7
      int ss = s ^ (r & 7);                // pre-swizzled source slot
      gll16(A + (size_t)(row0 + r) * K + k0 + ss * 8, At + (w * 4 + t) * 512);
      gll16(BT + (size_t)(col0 + r) * K + k0 + ss * 8, Bt + (w * 4 + t) * 512);
    }
    __syncthreads();
#pragma unroll
    for (int kk = 0; kk < 2; ++kk) {
      bf16x8 af[4], bfr[4];
#pragma unroll
      for (int mi = 0; mi < 4; ++mi) {
        int row = wr * 64 + mi * 16 + i;
        af[mi] = *(const bf16x8*)(At + row * 64 + (((kk * 4 + g) ^ (row & 7)) * 8));
      }
#pragma unroll
      for (int ni = 0; ni < 4; ++ni) {
        int row = wc * 64 + ni * 16 + i;
        bfr[ni] = *(const bf16x8*)(Bt + row * 64 + (((kk * 4 + g) ^ (row & 7)) * 8));
      }
#pragma unroll
      for (int mi = 0; mi < 4; ++mi)
#pragma unroll
        for (int ni = 0; ni < 4; ++ni)
          acc[mi][ni] = __builtin_amdgcn_mfma_f32_16x16x32_bf16(af[mi], bfr[ni],
                                                                acc[mi][ni], 0, 0, 0);
    }
    __syncthreads();
  }
  // epilogue: D row = 4*(lane>>4)+reg, col = lane&15 (verified m89/m91 layout)
#pragma unroll
  for (int mi = 0; mi < 4; ++mi)
#pragma unroll
    for (int ni = 0; ni < 4; ++ni) {
      int r_ = row0 + wr * 64 + mi * 16 + g * 4;
      int c_ = col0 + wc * 64 + ni * 16 + i;
#pragma unroll
      for (int r = 0; r < 4; ++r) {
        if (OUT_BF16)
          ((ushort*)Cv)[(size_t)(r_ + r) * N + c_] = f2bf(acc[mi][ni][r]);
        else
          ((float*)Cv)[(size_t)(r_ + r) * N + c_] = acc[mi][ni][r];
      }
    }
}

// ---------------- flash causal GQA attention (swapped-operand) -------------
// 512 blocks, hk=b&7 XCD-pinned, heavy-first. KVBLK=64. S^T = K·Q^T;
// softmax per q-column (2 shfls); P bounce q-major [32][72]: ushort4 writes,
// b128 frag reads; O^T += V^T·P^T; epilogue transposes O via LDS bounce.
__global__ __launch_bounds__(256) void attn_fwd(const ushort* __restrict__ QKV,
                                                const ushort* __restrict__ VTg,
                                                ushort* __restrict__ AO) {
  __shared__ __align__(16) char smem[32768];
  __shared__ __align__(16) ushort Pt[4][32 * 72];  // per-wave P [32 q][64 kv], stride 72
  char* Ks = smem;            // [64 kv][256B], swz ((row&7)<<4)
  char* Vs = smem + 16384;    // [128 d][128B], swz ((d&7)<<4)
  const int tid = threadIdx.x;
  const int lane = tid & 63, w = tid >> 6;
  const int g = lane >> 4, i = lane & 15;

  const int b = blockIdx.x;
  const int hk = b & 7;
  const int idx = b >> 3;                 // 0..63
  const int h = hk * 4 + (idx & 3);
  const int qt = 15 - (idx >> 2);         // heavy-first
  const int qb = qt * 128 + w * 32;
  const float scale = 0.08838834764831845f;  // 128^-0.5
  const float NEGINF = -1.0e30f;

  const ushort* Kg = QKV + 4096 + hk * HDIM;
  const ushort* Vg = VTg + (size_t)hk * 262144;
  ushort* Pw = Pt[w];

  // Q^T B-frags in registers: lane (g,i) holds Q[qb+nt*16+i][ks*32+g*8+j]
  bf16x8 qf[2][4];
#pragma unroll
  for (int nt = 0; nt < 2; ++nt)
#pragma unroll
    for (int ks = 0; ks < 4; ++ks)
      qf[nt][ks] = *(const bf16x8*)(QKV + (size_t)(qb + nt * 16 + i) * EQKV +
                                    h * HDIM + ks * 32 + g * 8);

  f32x4 ot[8][2] = {};           // O^T frags: [d-tile][q-tile]
  float m_i[2] = {-1.0e30f, -1.0e30f}, l_i[2] = {0.f, 0.f};

  const int nkb = (qt + 1) * 2;  // kv64 blocks up to diagonal of the block
  for (int kb = 0; kb < nkb; ++kb) {
    const int kv0 = kb * 64;
    // ---- stage K [64][128] and V^T [128][64], both vectorized + swizzled --
#pragma unroll
    for (int t = 0; t < 4; ++t) {
      int C = t * 256 + tid;
      int row = C >> 4, slot = C & 15;
      uint4 kv = *(const uint4*)(Kg + (size_t)(kv0 + row) * EQKV + slot * 8);
      *(uint4*)(Ks + row * 256 + ((slot * 16) ^ ((row & 7) << 4))) = kv;
      int d = C >> 3, sl = C & 7;
      uint4 vv = *(const uint4*)(Vg + (size_t)d * 2048 + kv0 + sl * 8);
      *(uint4*)(Vs + d * 128 + ((sl * 16) ^ ((d & 7) << 4))) = vv;
    }
    __syncthreads();
    if (kv0 <= qb + 31) {   // wave-uniform causal skip
      // ---- S^T = K Q^T : rows kv (4 m-tiles), cols q (2 n-tiles) ----
      f32x4 st[4][2] = {};
#pragma unroll
      for (int ks = 0; ks < 4; ++ks)
#pragma unroll
        for (int mt = 0; mt < 4; ++mt) {
          int row = mt * 16 + i;
          bf16x8 kf = *(const bf16x8*)(Ks + row * 256 +
                                       ((ks * 64 + g * 16) ^ ((row & 7) << 4)));
#pragma unroll
          for (int nt = 0; nt < 2; ++nt)
            st[mt][nt] = __builtin_amdgcn_mfma_f32_16x16x32_bf16(kf, qf[nt][ks],
                                                                 st[mt][nt], 0, 0, 0);
        }
      // ---- per-q-column online softmax (lane holds 16 of 64 kv) ----
      float al[2];
#pragma unroll
      for (int nt = 0; nt < 2; ++nt) {
        const int qg = qb + nt * 16 + i;
        float ps[4][4];
        float tm = NEGINF;
#pragma unroll
        for (int mt = 0; mt < 4; ++mt)
#pragma unroll
          for (int r = 0; r < 4; ++r) {
            int kvg = kv0 + mt * 16 + g * 4 + r;
            float s = st[mt][nt][r] * scale;
            s = (kvg > qg) ? NEGINF : s;
            ps[mt][r] = s;
            tm = fmaxf(tm, s);
          }
        tm = fmaxf(tm, __shfl_xor(tm, 16));
        tm = fmaxf(tm, __shfl_xor(tm, 32));
        float mn = fmaxf(m_i[nt], tm);
        float a = __expf(m_i[nt] - mn);
        float rs = 0.f;
#pragma unroll
        for (int mt = 0; mt < 4; ++mt)
#pragma unroll
          for (int r = 0; r < 4; ++r) {
            ps[mt][r] = __expf(ps[mt][r] - mn);
            rs += ps[mt][r];
          }
        rs += __shfl_xor(rs, 16);
        rs += __shfl_xor(rs, 32);
        l_i[nt] = l_i[nt] * a + rs;
        m_i[nt] = mn;
        al[nt] = a;
        // ---- P row (q-major) -> LDS, vectorized ushort4 per (nt,mt) ----
#pragma unroll
        for (int mt = 0; mt < 4; ++mt) {
          ushort4 p4;
          p4.x = f2bf(ps[mt][0]); p4.y = f2bf(ps[mt][1]);
          p4.z = f2bf(ps[mt][2]); p4.w = f2bf(ps[mt][3]);
          *(ushort4*)&Pw[(nt * 16 + i) * 72 + mt * 16 + g * 4] = p4;
        }
      }
      // ---- rescale O^T ----
#pragma unroll
      for (int md = 0; md < 8; ++md)
#pragma unroll
        for (int nt = 0; nt < 2; ++nt)
#pragma unroll
          for (int r = 0; r < 4; ++r)
            ot[md][nt][r] *= al[nt];
      // ---- P^T B-frags: b128 reads (same-wave RAW, no barrier needed) ----
      // frag elem j = P[q=nt*16+i][kv=kst*32+g*8+j]
      bf16x8 ptf[2][2];
#pragma unroll
      for (int kst = 0; kst < 2; ++kst)
#pragma unroll
        for (int nt = 0; nt < 2; ++nt)
          ptf[kst][nt] = *(const bf16x8*)&Pw[(nt * 16 + i) * 72 + kst * 32 + g * 8];
      // ---- O^T += V^T P^T ----
#pragma unroll
      for (int md = 0; md < 8; ++md)
#pragma unroll
        for (int kst = 0; kst < 2; ++kst) {
          int row = md * 16 + i;
          bf16x8 vf = *(const bf16x8*)(Vs + row * 128 +
                                       ((kst * 64 + g * 16) ^ ((row & 7) << 4)));
#pragma unroll
          for (int nt = 0; nt < 2; ++nt)
            ot[md][nt] = __builtin_amdgcn_mfma_f32_16x16x32_bf16(vf, ptf[kst][nt],
                                                                 ot[md][nt], 0, 0, 0);
        }
    }
    __syncthreads();
  }
  // ---- epilogue: O^T/l -> per-wave LDS bounce -> coalesced AO stores ----
  char* Sw = smem + w * 8192;   // [32 q][256B] swz ((q&7)<<4)
#pragma unroll
  for (int md = 0; md < 8; ++md)
#pragma unroll
    for (int nt = 0; nt < 2; ++nt)
#pragma unroll
      for (int r = 0; r < 4; ++r) {
        int row = nt * 16 + i, col = md * 16 + g * 4 + r;
        *(ushort*)(Sw + row * 256 + ((col * 2) ^ ((row & 7) << 4))) =
            f2bf(ot[md][nt][r] / l_i[nt]);
      }
#pragma unroll
  for (int t = 0; t < 8; ++t) {
    int c = t * 64 + lane;
    int row = c >> 4, sl = c & 15;
    uint4 v = *(const uint4*)(Sw + row * 256 + ((sl * 16) ^ ((row & 7) << 4)));
    *(uint4*)(AO + (size_t)(qb + row) * DMODEL + h * HDIM + sl * 8) = v;
  }
}

// ---------------------------------------------------------------------------
extern "C" void kernel_launch(void* const* d_in, const int* in_sizes, int n_in,
                              void* d_out, int out_size, void* d_ws, size_t ws_size,
                              hipStream_t stream) {
  const float* hidden = (const float*)d_in[1];
  const float* Wqkv   = (const float*)d_in[2];
  const float* Wo     = (const float*)d_in[3];
  float* out = (float*)d_out;

  char* ws = (char*)d_ws;
  // workspace layout (bytes)
  const size_t off_Xb    = 0;                       // 16 MiB (VTg overlays after gemm1)
  const size_t off_QKV   = 16777216;                // 24 MiB
  const size_t off_AO    = 41943040;                // 16 MiB
  const size_t off_WqkvT = 58720256;                // 48 MiB
  const size_t off_WoT   = 109051904;               // 32 MiB
  ushort* Xb    = (ushort*)(ws + off_Xb);
  ushort* VTg   = (ushort*)(ws + off_Xb);           // reuse: 4 MiB, after gemm1
  ushort* QKVb  = (ushort*)(ws + off_QKV);
  ushort* AO    = (ushort*)(ws + off_AO);
  ushort* WqkvT = (ushort*)(ws + off_WqkvT);
  ushort* WoT   = (ushort*)(ws + off_WoT);

  // 1. convert hidden -> bf16
  cvt_f32_bf16<<<(S_LEN * DMODEL / 4 + 255) / 256, 256, 0, stream>>>(
      hidden, Xb, S_LEN * DMODEL / 4);
  // 2. transpose-convert weights: W [K][N] fp32 -> WT [N][K] bf16
  transpose_cvt<<<dim3(DMODEL / 32, EQKV / 32), 256, 0, stream>>>(Wqkv, WqkvT,
                                                                  DMODEL, EQKV);
  transpose_cvt<<<dim3(DMODEL / 32, DMODEL / 32), 256, 0, stream>>>(Wo, WoT,
                                                                    DMODEL, DMODEL);
  // 3. QKV = X @ Wqkv   (bf16 out)
  gemm_bt<true><<<768, 256, 0, stream>>>(Xb, WqkvT, (void*)QKVb,
                                         S_LEN, EQKV, DMODEL, 16);
  // 4. V^T pre-transpose (4 MiB, overlays Xb)
  vtrans<<<dim3(32, 16), 256, 0, stream>>>(QKVb, VTg);
  // 5. flash causal GQA attention
  attn_fwd<<<512, 256, 0, stream>>>(QKVb, VTg, AO);
  // 6. out = AO @ Wo    (fp32 out)
  gemm_bt<false><<<512, 256, 0, stream>>>(AO, WoT, (void*)out,
                                          S_LEN, DMODEL, DMODEL, 16);
}